// Round 5
// baseline (260.215 us; speedup 1.0000x reference)
//
#include <hip/hip_runtime.h>
#include <hip/hip_bf16.h>

#define BATCH 8192
#define DIM   1024
#define INV_TAU (1.0f / 0.07f)
#define TOPM 0.95f
#define BOTM 0.05f

#define BM 256
#define BN 256
#define BK 64
#define NT (DIM / BK)   // 16 K-tiles per output tile

typedef __attribute__((ext_vector_type(4))) float f32x4;
typedef __attribute__((ext_vector_type(8))) short bf16x8;

typedef __attribute__((address_space(3))) void       lds_void_t;
typedef const __attribute__((address_space(1))) void gbl_void_t;

__device__ inline void async_copy16(const void* g, void* l) {
    __builtin_amdgcn_global_load_lds((gbl_void_t*)g, (lds_void_t*)l, 16, 0, 0);
}

__device__ inline unsigned short f2bf(float f) {
    __hip_bfloat16 h = __float2bfloat16(f);
    return *reinterpret_cast<unsigned short*>(&h);
}

// ---------------------------------------------------------------------------
// Kernel 1: per-row L2 norms, exact fp32 pos, bf16 writes, zero-init S.
// ---------------------------------------------------------------------------
__global__ __launch_bounds__(256) void prep_kernel(
    const float* __restrict__ A, const float* __restrict__ B,
    unsigned short* __restrict__ An, unsigned short* __restrict__ Bn,
    float* __restrict__ pos, float* __restrict__ S)
{
    int row = blockIdx.x;
    int t = threadIdx.x;
    const float4* a4 = (const float4*)(A + (size_t)row * DIM);
    const float4* b4 = (const float4*)(B + (size_t)row * DIM);
    float4 av = a4[t];
    float4 bv = b4[t];
    float sa = av.x*av.x + av.y*av.y + av.z*av.z + av.w*av.w;
    float sb = bv.x*bv.x + bv.y*bv.y + bv.z*bv.z + bv.w*bv.w;
    float dp = av.x*bv.x + av.y*bv.y + av.z*bv.z + av.w*bv.w;
    #pragma unroll
    for (int d = 32; d > 0; d >>= 1) {
        sa += __shfl_down(sa, d);
        sb += __shfl_down(sb, d);
        dp += __shfl_down(dp, d);
    }
    __shared__ float red[3][4];
    int lane = t & 63, w = t >> 6;
    if (lane == 0) { red[0][w] = sa; red[1][w] = sb; red[2][w] = dp; }
    __syncthreads();
    sa = red[0][0] + red[0][1] + red[0][2] + red[0][3];
    sb = red[1][0] + red[1][1] + red[1][2] + red[1][3];
    dp = red[2][0] + red[2][1] + red[2][2] + red[2][3];
    float ra = rsqrtf(sa);
    float rb = rsqrtf(sb);
    if (t == 0) {
        pos[row] = dp * ra * rb;
        S[row] = 0.0f;
    }
    ushort4 oa, ob;
    oa.x = f2bf(av.x * ra); oa.y = f2bf(av.y * ra);
    oa.z = f2bf(av.z * ra); oa.w = f2bf(av.w * ra);
    ob.x = f2bf(bv.x * rb); ob.y = f2bf(bv.y * rb);
    ob.z = f2bf(bv.z * rb); ob.w = f2bf(bv.w * rb);
    ((ushort4*)(An + (size_t)row * DIM))[t] = oa;
    ((ushort4*)(Bn + (size_t)row * DIM))[t] = ob;
}

// ---------------------------------------------------------------------------
// Kernel 2: PERSISTENT 256x256 pipelined MFMA GEMM + fused masked exp-sum,
// now with REGISTER-LEVEL ds_read pipelining: each phase issues the NEXT
// phase's fragment reads before its own MFMA, counted lgkm waits drain only
// the one-phase-old reads, so LDS service overlaps the MFMA clusters.
//
// Per K-tile t (buffer p=t&1; quadrants (mh,nh) in order 00,01,11,10):
//  P1: issue ds b1[p](4);      stage A(t+1)h1; LGKM(4)  [a0,b0 done]; MM00; BAR
//  P2: issue ds a1[p](8);                      LGKM(8)  [b1 done];    MM01;
//      VMC(0) [A(t+1)+B(t+1) done, youngest ~2 phases old];           BAR
//  P3: issue ds a0'[p^1](8);   stage B(t+2)h0; LGKM(8)  [a1 done];    MM11; BAR
//  P4: issue ds b0'[p^1](4);   stage B(t+2)h1 + A(t+2)h0; (no wait);  MM10; BAR
// B-fragment arrays swap roles (Bx/By) each tile so b0' lands in the array
// whose last use was P3 (zero extra registers, no WAR conflict).
// Stage-over-read safety: every stage to a buffer is issued after the BAR
// that follows the draining of ALL waves' last reads of that buffer
// (A(t+1)h1@P1 > BAR(t-1 P3) where a1 drained; B(t+2)h0@P3 > BAR(P2) where
// b1 drained; A(t+2)h0@P4 > BAR(P3) where a1 drained).
// ---------------------------------------------------------------------------
__global__ __launch_bounds__(512, 2) void sim_loss_kernel(
    const unsigned short* __restrict__ An, const unsigned short* __restrict__ Bn,
    const float* __restrict__ pos, float* __restrict__ S)
{
    __shared__ char lds[131072];   // A[2]: 0,32768 ; B[2]: 65536, 98304

    int tid  = threadIdx.x;
    int lane = tid & 63;
    int wave = tid >> 6;
    int wm = wave >> 2, wn = wave & 3;   // 2x4 wave grid, 128x64 per wave
    int fr = lane & 15;
    int q  = lane >> 4;

    int bid = blockIdx.x;   // 0..255

#define BASES(g, rB, cB) do {                                                        \
    int xcd_ = bid & 7, jj_ = bid >> 3;                                              \
    int qr_ = (g) >> 1, qc_ = ((g) & 1) ^ (qr_ & 1);                                 \
    (rB) = (qr_ * 16 + (xcd_ >> 1) * 4 + (jj_ >> 3)) * BM;                           \
    (cB) = (qc_ * 16 + (xcd_ & 1) * 8 + (jj_ & 7)) * BN;                             \
} while (0)

    f32x4 acc[8][4] = {};
    bf16x8 A0[4][2];   // mh0 fragments (current tile)
    bf16x8 A1[4][2];   // mh1 fragments (current tile)
    bf16x8 Bx[2][2];   // even tiles: b0(nh0); odd tiles: b1(nh1)
    bf16x8 By[2][2];   // even tiles: b1(nh1); odd tiles: b0(nh0)

    // ds_read addressing (read-side swizzle)
    int sw = (fr & 7) << 4;
    int c0 = (q * 16) ^ sw;
    int c1 = (64 + q * 16) ^ sw;
    int aRow = (wm * 128 + fr) * 128;
    int bRow = (wn * 64 + fr) * 128;

    // staging addressing (source-side swizzle, linear LDS dest)
    int strow = tid >> 3;                                  // 0..63
    int scb   = ((tid & 7) * 16) ^ ((strow & 7) << 4);
    int ldst = tid * 16;

#define PANELS(rB, cB, pA, pB) do {                                                  \
    (pA) = (const char*)An + (size_t)((rB) + strow) * 2048 + scb;                    \
    (pB) = (const char*)Bn + (size_t)((cB) + strow) * 2048 + scb;                    \
} while (0)

#define STAGE(gbase, u, h, ldsdst) do {                                              \
    async_copy16((gbase) + (size_t)(h) * 262144 + (size_t)(u) * 128,                 \
                 (ldsdst) + (h) * 16384 + ldst);                                     \
    async_copy16((gbase) + (size_t)(h) * 262144 + 131072 + (size_t)(u) * 128,        \
                 (ldsdst) + (h) * 16384 + 8192 + ldst);                              \
} while (0)

#define LDA_(arr, p, mh) do {                                                        \
    const char* _s = lds + (p) * 32768;                                              \
    _Pragma("unroll") for (int m = 0; m < 4; ++m) {                                  \
        arr[m][0] = *(const bf16x8*)(_s + aRow + (mh) * 8192 + m * 2048 + c0);       \
        arr[m][1] = *(const bf16x8*)(_s + aRow + (mh) * 8192 + m * 2048 + c1);       \
    }                                                                                \
} while (0)

#define LDB_(arr, p, nh) do {                                                        \
    const char* _s = lds + 65536 + (p) * 32768;                                      \
    _Pragma("unroll") for (int n = 0; n < 2; ++n) {                                  \
        arr[n][0] = *(const bf16x8*)(_s + bRow + (nh) * 4096 + n * 2048 + c0);       \
        arr[n][1] = *(const bf16x8*)(_s + bRow + (nh) * 4096 + n * 2048 + c1);       \
    }                                                                                \
} while (0)

#define MM_(aarr, barr, mo, no) do {                                                 \
    _Pragma("unroll") for (int m = 0; m < 4; ++m)                                    \
    _Pragma("unroll") for (int n = 0; n < 2; ++n) {                                  \
        acc[(mo)+m][(no)+n] = __builtin_amdgcn_mfma_f32_16x16x32_bf16(               \
            aarr[m][0], barr[n][0], acc[(mo)+m][(no)+n], 0, 0, 0);                   \
        acc[(mo)+m][(no)+n] = __builtin_amdgcn_mfma_f32_16x16x32_bf16(               \
            aarr[m][1], barr[n][1], acc[(mo)+m][(no)+n], 0, 0, 0);                   \
    }                                                                                \
} while (0)

#define BAR() __builtin_amdgcn_s_barrier()
#define SCH() __builtin_amdgcn_sched_barrier(0)
#define LGKM(n) do { asm volatile("s_waitcnt lgkmcnt(" #n ")" ::: "memory");         \
                     SCH(); } while (0)
#define VMC(n)  asm volatile("s_waitcnt vmcnt(" #n ")" ::: "memory")
#define PRI1() __builtin_amdgcn_s_setprio(1)
#define PRI0() __builtin_amdgcn_s_setprio(0)

// B0A holds this tile's b0 data; B1A receives b1 (P1) and next-tile b0 (P4).
#define KTILE(p, B0A, B1A, pA1, u1, pB2, u2, pA2, u3) do {                           \
    char* stA1 = lds + ((p) ^ 1) * 32768;                                            \
    char* stB  = lds + 65536 + (p) * 32768;                                          \
    char* stA2 = lds + (p) * 32768;                                                  \
    /* P1 */ LDB_(B1A, (p), 1); STAGE((pA1), (u1), 1, stA1);                         \
    LGKM(4); PRI1(); MM_(A0, B0A, 0, 0); PRI0(); SCH(); BAR(); SCH();                \
    /* P2 */ LDA_(A1, (p), 1);                                                       \
    LGKM(8); PRI1(); MM_(A0, B1A, 0, 2); PRI0(); VMC(0); SCH(); BAR(); SCH();        \
    /* P3 */ LDA_(A0, (p) ^ 1, 0); STAGE((pB2), (u2), 0, stB);                       \
    LGKM(8); PRI1(); MM_(A1, B1A, 4, 2); PRI0(); SCH(); BAR(); SCH();                \
    /* P4 */ LDB_(B1A, (p) ^ 1, 0); STAGE((pB2), (u2), 1, stB);                      \
    STAGE((pA2), (u3), 0, stA2);                                                     \
    PRI1(); MM_(A1, B0A, 4, 0); PRI0(); SCH(); BAR(); SCH();                         \
} while (0)

    int rowB, colB;
    BASES(0, rowB, colB);
    const char *gAc, *gBc;
    PANELS(rowB, colB, gAc, gBc);

    // Prologue: A(0),B(0),B(1) full + A(1)h0; drain A(0),B(0) (leave 6);
    // pre-issue tile0's a0,b0 ds reads (the steady "prev P3/P4" reads).
    STAGE(gAc, 0, 0, lds);
    STAGE(gAc, 0, 1, lds);
    STAGE(gBc, 0, 0, lds + 65536);
    STAGE(gBc, 0, 1, lds + 65536);
    STAGE(gBc, 1, 0, lds + 98304);
    STAGE(gBc, 1, 1, lds + 98304);
    STAGE(gAc, 1, 0, lds + 32768);
    VMC(6);
    BAR();
    SCH();
    LDA_(A0, 0, 0);   // tile0 a0 (8 reads)
    LDB_(Bx, 0, 0);   // tile0 b0 (4 reads)

    #pragma unroll 1
    for (int g = 0; g < 4; ++g) {
        int gn = (g < 3) ? g + 1 : 3;
        int rowBn, colBn;
        BASES(gn, rowBn, colBn);
        const char *gAn2, *gBn2;
        PANELS(rowBn, colBn, gAn2, gBn2);

        #pragma unroll 1
        for (int tt = 0; tt < 7; ++tt) {
            int t0 = 2 * tt;
            KTILE(0, Bx, By, gAc, t0 + 1, gBc, t0 + 2, gAc, t0 + 2);
            KTILE(1, By, Bx, gAc, t0 + 2, gBc, t0 + 3, gAc, t0 + 3);
        }
        // t=14: B(16)/A(16) wrap to next tile's panels (u=0)
        KTILE(0, Bx, By, gAc, 15, gBn2, 0, gAn2, 0);
        // t=15: A(16)h1 -> next u0; B(17)/A(17) -> next u1
        KTILE(1, By, Bx, gAn2, 0, gBn2, 1, gAn2, 1);

        // Epilogue for tile g (next tile's first a0/b0 ds reads in flight).
        #pragma unroll
        for (int m = 0; m < 8; ++m) {
            #pragma unroll
            for (int j2 = 0; j2 < 4; ++j2) {
                int i = rowB + wm * 128 + m * 16 + q * 4 + j2;
                float p  = pos[i];
                float up = TOPM * p, lo = BOTM * p;
                float rs = 0.0f;
                #pragma unroll
                for (int n = 0; n < 4; ++n) {
                    float sv = acc[m][n][j2];
                    int col = colB + wn * 64 + n * 16 + fr;
                    if (sv <= up && sv >= lo && col != i)
                        rs += __expf((sv - p) * INV_TAU);
                }
                #pragma unroll
                for (int d = 1; d < 16; d <<= 1)
                    rs += __shfl_xor(rs, d);
                if (fr == 0 && rs != 0.0f)
                    atomicAdd(&S[i], rs);
            }
        }
        #pragma unroll
        for (int m2 = 0; m2 < 8; ++m2)
            #pragma unroll
            for (int n2 = 0; n2 < 4; ++n2)
                acc[m2][n2] = (f32x4){0.0f, 0.0f, 0.0f, 0.0f};

        gAc = gAn2; gBc = gBn2; rowB = rowBn; colB = colBn;
    }
    LGKM(0);   // drain dangling pre-issued reads of the final wrap
    VMC(0);    // drain redundant g=3 staging + atomics before endpgm

#undef BASES
#undef PANELS
#undef STAGE
#undef LDA_
#undef LDB_
#undef MM_
#undef BAR
#undef SCH
#undef LGKM
#undef VMC
#undef PRI1
#undef PRI0
#undef KTILE
}

// ---------------------------------------------------------------------------
// Kernel 3: per_row = log1p(S_i) for rows with any negative; mean over valid.
// ---------------------------------------------------------------------------
__global__ __launch_bounds__(256) void finalize_kernel(
    const float* __restrict__ S, float* __restrict__ out)
{
    int t = threadIdx.x;
    float tot = 0.0f;
    int c = 0;
    for (int i = t; i < BATCH; i += 256) {
        float s = S[i];
        if (s > 0.0f) { tot += log1pf(s); c += 1; }
    }
    #pragma unroll
    for (int d = 32; d > 0; d >>= 1) {
        tot += __shfl_down(tot, d);
        c   += __shfl_down(c, d);
    }
    __shared__ float st[4];
    __shared__ int   sc[4];
    int lane = t & 63, w = t >> 6;
    if (lane == 0) { st[w] = tot; sc[w] = c; }
    __syncthreads();
    if (t == 0) {
        float T = st[0] + st[1] + st[2] + st[3];
        int   C = sc[0] + sc[1] + sc[2] + sc[3];
        out[0] = T / (float)(C > 0 ? C : 1);
    }
}

extern "C" void kernel_launch(void* const* d_in, const int* in_sizes, int n_in,
                              void* d_out, int out_size, void* d_ws, size_t ws_size,
                              hipStream_t stream) {
    const float* A = (const float*)d_in[0];
    const float* B = (const float*)d_in[1];

    char* ws = (char*)d_ws;
    unsigned short* An = (unsigned short*)ws;
    unsigned short* Bn = An + (size_t)BATCH * DIM;
    float* pos = (float*)(Bn + (size_t)BATCH * DIM);
    float* S   = pos + BATCH;
    float* out = (float*)d_out;

    prep_kernel<<<BATCH, 256, 0, stream>>>(A, B, An, Bn, pos, S);
    sim_loss_kernel<<<256, 512, 0, stream>>>(An, Bn, pos, S);
    finalize_kernel<<<1, 256, 0, stream>>>(S, out);
}

// Round 6
// 210.747 us; speedup vs baseline: 1.2347x; 1.2347x over previous
//
#include <hip/hip_runtime.h>
#include <hip/hip_bf16.h>

#define BATCH 8192
#define DIM   1024
#define INV_TAU (1.0f / 0.07f)
#define TOPM 0.95f
#define BOTM 0.05f

#define BM 256
#define BN 256
#define BK 64
#define NT (DIM / BK)   // 16 K-tiles per output tile

typedef __attribute__((ext_vector_type(4))) float f32x4;
typedef __attribute__((ext_vector_type(8))) short bf16x8;

typedef __attribute__((address_space(3))) void       lds_void_t;
typedef const __attribute__((address_space(1))) void gbl_void_t;

__device__ inline void async_copy16(const void* g, void* l) {
    __builtin_amdgcn_global_load_lds((gbl_void_t*)g, (lds_void_t*)l, 16, 0, 0);
}

__device__ inline unsigned short f2bf(float f) {
    __hip_bfloat16 h = __float2bfloat16(f);
    return *reinterpret_cast<unsigned short*>(&h);
}

// ---------------------------------------------------------------------------
// Kernel 1: per-row L2 norms, exact fp32 pos, bf16 writes, zero-init S.
// ---------------------------------------------------------------------------
__global__ __launch_bounds__(256) void prep_kernel(
    const float* __restrict__ A, const float* __restrict__ B,
    unsigned short* __restrict__ An, unsigned short* __restrict__ Bn,
    float* __restrict__ pos, float* __restrict__ S)
{
    int row = blockIdx.x;
    int t = threadIdx.x;
    const float4* a4 = (const float4*)(A + (size_t)row * DIM);
    const float4* b4 = (const float4*)(B + (size_t)row * DIM);
    float4 av = a4[t];
    float4 bv = b4[t];
    float sa = av.x*av.x + av.y*av.y + av.z*av.z + av.w*av.w;
    float sb = bv.x*bv.x + bv.y*bv.y + bv.z*bv.z + bv.w*bv.w;
    float dp = av.x*bv.x + av.y*bv.y + av.z*bv.z + av.w*bv.w;
    #pragma unroll
    for (int d = 32; d > 0; d >>= 1) {
        sa += __shfl_down(sa, d);
        sb += __shfl_down(sb, d);
        dp += __shfl_down(dp, d);
    }
    __shared__ float red[3][4];
    int lane = t & 63, w = t >> 6;
    if (lane == 0) { red[0][w] = sa; red[1][w] = sb; red[2][w] = dp; }
    __syncthreads();
    sa = red[0][0] + red[0][1] + red[0][2] + red[0][3];
    sb = red[1][0] + red[1][1] + red[1][2] + red[1][3];
    dp = red[2][0] + red[2][1] + red[2][2] + red[2][3];
    float ra = rsqrtf(sa);
    float rb = rsqrtf(sb);
    if (t == 0) {
        pos[row] = dp * ra * rb;
        S[row] = 0.0f;
    }
    ushort4 oa, ob;
    oa.x = f2bf(av.x * ra); oa.y = f2bf(av.y * ra);
    oa.z = f2bf(av.z * ra); oa.w = f2bf(av.w * ra);
    ob.x = f2bf(bv.x * rb); ob.y = f2bf(bv.y * rb);
    ob.z = f2bf(bv.z * rb); ob.w = f2bf(bv.w * rb);
    ((ushort4*)(An + (size_t)row * DIM))[t] = oa;
    ((ushort4*)(Bn + (size_t)row * DIM))[t] = ob;
}

// ---------------------------------------------------------------------------
// Kernel 2: PERSISTENT 256x256 MFMA GEMM + fused masked exp-sum, m201-style
// phase body: per phase {subtile ds_reads + 2 global_load_lds -> s_barrier ->
// lgkmcnt(0)+sched_barrier -> setprio(1)+16 MFMA+setprio(0) -> s_barrier}.
// Early-queued waves clear lgkmcnt(0) and MFMA while LDS serves later waves.
//
// Per K-tile t (p=t&1; read A[p],B[p]; stage t+1 into ^1 buffers):
//  phA (mh0,nh0): ds a0(8)+b0(4)=12; stage B(t+1)h0; LGKM(8); bar; lgkm0;
//                 MM(a,b0,quad00); bar
//  phB (mh0,nh1): ds b1(4);          stage B(t+1)h1;          bar; lgkm0;
//                 MM(a,b1,quad01); VMC(4); bar
//  phC (mh1,nh1): ds a1(8);          stage A(t+1)h0;          bar; lgkm0;
//                 MM(a,b1,quad11); bar
//  phD (mh1,nh0): (no ds);           stage A(t+1)h1;          bar;
//                 MM(a,b0,quad10); VMC(2); bar
// vmcnt ledger (issue order B h0,B h1,A h0,A h1 per tile, 2 loads each):
//  VMC(2)@D(t): outstanding 8 -> drains B(t+1)+A(t+1)h0, leaves A(t+1)h1.
//    Gates tile-t+1 phA reads (a0,b0) issued after bar2(D,t).  OK.
//  VMC(4)@B(t+1): outstanding A(t+1)h1:2 + B(t+2)h0:2 + h1:2 = 6 -> drains
//    A(t+1)h1.  Gates phC(t+1)'s a1 reads issued after bar2(B,t+1).  OK.
// Stage-over-read WAR: stages to buffer X are issued >= 1 barrier after the
// lgkm0 that drained the last reads of X (checked per phase).  Epilogue
// atomics inflate vmcnt once per output tile; VMC over-drain is safe.
// ---------------------------------------------------------------------------
__global__ __launch_bounds__(512, 2) void sim_loss_kernel(
    const unsigned short* __restrict__ An, const unsigned short* __restrict__ Bn,
    const float* __restrict__ pos, float* __restrict__ S)
{
    __shared__ char lds[131072];   // A[2]: 0,32768 ; B[2]: 65536, 98304

    int tid  = threadIdx.x;
    int lane = tid & 63;
    int wave = tid >> 6;
    int wm = wave >> 2, wn = wave & 3;   // 2x4 wave grid, 128x64 per wave
    int fr = lane & 15;
    int q  = lane >> 4;

    int bid = blockIdx.x;   // 0..255

#define BASES(g, rB, cB) do {                                                        \
    int xcd_ = bid & 7, jj_ = bid >> 3;                                              \
    int qr_ = (g) >> 1, qc_ = ((g) & 1) ^ (qr_ & 1);                                 \
    (rB) = (qr_ * 16 + (xcd_ >> 1) * 4 + (jj_ >> 3)) * BM;                           \
    (cB) = (qc_ * 16 + (xcd_ & 1) * 8 + (jj_ & 7)) * BN;                             \
} while (0)

    f32x4 acc[8][4] = {};
    bf16x8 a[4][2];      // current mh half: 4 m-frags x 2 k-slices
    bf16x8 b0[2][2];     // nh0 fragments (held phA..phD)
    bf16x8 b1[2][2];     // nh1 fragments (held phB..phC)

    // ds_read addressing (read-side swizzle)
    int sw = (fr & 7) << 4;
    int c0 = (q * 16) ^ sw;
    int c1 = (64 + q * 16) ^ sw;
    int aRow = (wm * 128 + fr) * 128;
    int bRow = (wn * 64 + fr) * 128;

    // staging addressing (source-side swizzle, linear LDS dest)
    int strow = tid >> 3;                                  // 0..63
    int scb   = ((tid & 7) * 16) ^ ((strow & 7) << 4);
    int ldst = tid * 16;

#define PANELS(rB, cB, pA, pB) do {                                                  \
    (pA) = (const char*)An + (size_t)((rB) + strow) * 2048 + scb;                    \
    (pB) = (const char*)Bn + (size_t)((cB) + strow) * 2048 + scb;                    \
} while (0)

#define STAGE(gbase, u, h, ldsdst) do {                                              \
    async_copy16((gbase) + (size_t)(h) * 262144 + (size_t)(u) * 128,                 \
                 (ldsdst) + (h) * 16384 + ldst);                                     \
    async_copy16((gbase) + (size_t)(h) * 262144 + 131072 + (size_t)(u) * 128,        \
                 (ldsdst) + (h) * 16384 + 8192 + ldst);                              \
} while (0)

#define LDA_(p, mh) do {                                                             \
    const char* _s = lds + (p) * 32768;                                              \
    _Pragma("unroll") for (int m = 0; m < 4; ++m) {                                  \
        a[m][0] = *(const bf16x8*)(_s + aRow + (mh) * 8192 + m * 2048 + c0);         \
        a[m][1] = *(const bf16x8*)(_s + aRow + (mh) * 8192 + m * 2048 + c1);         \
    }                                                                                \
} while (0)

#define LDB_(arr, p, nh) do {                                                        \
    const char* _s = lds + 65536 + (p) * 32768;                                      \
    _Pragma("unroll") for (int n = 0; n < 2; ++n) {                                  \
        arr[n][0] = *(const bf16x8*)(_s + bRow + (nh) * 4096 + n * 2048 + c0);       \
        arr[n][1] = *(const bf16x8*)(_s + bRow + (nh) * 4096 + n * 2048 + c1);       \
    }                                                                                \
} while (0)

#define MM_(barr, mo, no) do {                                                       \
    _Pragma("unroll") for (int m = 0; m < 4; ++m)                                    \
    _Pragma("unroll") for (int n = 0; n < 2; ++n) {                                  \
        acc[(mo)+m][(no)+n] = __builtin_amdgcn_mfma_f32_16x16x32_bf16(               \
            a[m][0], barr[n][0], acc[(mo)+m][(no)+n], 0, 0, 0);                      \
        acc[(mo)+m][(no)+n] = __builtin_amdgcn_mfma_f32_16x16x32_bf16(               \
            a[m][1], barr[n][1], acc[(mo)+m][(no)+n], 0, 0, 0);                      \
    }                                                                                \
} while (0)

#define BAR() __builtin_amdgcn_s_barrier()
#define SCH() __builtin_amdgcn_sched_barrier(0)
#define LGKM(n) do { asm volatile("s_waitcnt lgkmcnt(" #n ")" ::: "memory");         \
                     SCH(); } while (0)
#define VMC(n)  asm volatile("s_waitcnt vmcnt(" #n ")" ::: "memory")
#define PRI1() __builtin_amdgcn_s_setprio(1)
#define PRI0() __builtin_amdgcn_s_setprio(0)

#define KTILE(p, pA_, uA, pB_, uB) do {                                              \
    char* stA = lds + ((p) ^ 1) * 32768;                                             \
    char* stB = lds + 65536 + ((p) ^ 1) * 32768;                                     \
    /* phA: quad(mh0,nh0) */                                                         \
    LDA_((p), 0); LDB_(b0, (p), 0); STAGE((pB_), (uB), 0, stB);                      \
    LGKM(8); BAR();                                                                  \
    LGKM(0); PRI1(); MM_(b0, 0, 0); PRI0(); BAR();                                   \
    /* phB: quad(mh0,nh1) */                                                         \
    LDB_(b1, (p), 1); STAGE((pB_), (uB), 1, stB);                                    \
    BAR();                                                                           \
    LGKM(0); PRI1(); MM_(b1, 0, 2); PRI0(); VMC(4); BAR();                           \
    /* phC: quad(mh1,nh1) */                                                         \
    LDA_((p), 1); STAGE((pA_), (uA), 0, stA);                                        \
    BAR();                                                                           \
    LGKM(0); PRI1(); MM_(b1, 4, 2); PRI0(); BAR();                                   \
    /* phD: quad(mh1,nh0) */                                                         \
    STAGE((pA_), (uA), 1, stA);                                                      \
    BAR();                                                                           \
    PRI1(); MM_(b0, 4, 0); PRI0(); VMC(2); BAR();                                    \
} while (0)

    int rowB, colB;
    BASES(0, rowB, colB);
    const char *gAc, *gBc;
    PANELS(rowB, colB, gAc, gBc);

    // Prologue (once): A(0)->A[0], B(0)->B[0]; full drain + barrier.
    STAGE(gAc, 0, 0, lds);
    STAGE(gAc, 0, 1, lds);
    STAGE(gBc, 0, 0, lds + 65536);
    STAGE(gBc, 0, 1, lds + 65536);
    VMC(0);
    BAR();

    #pragma unroll 1
    for (int g = 0; g < 4; ++g) {
        int gn = (g < 3) ? g + 1 : 3;
        int rowBn, colBn;
        BASES(gn, rowBn, colBn);
        const char *gAn2, *gBn2;
        PANELS(rowBn, colBn, gAn2, gBn2);

        #pragma unroll 1
        for (int tt = 0; tt < 7; ++tt) {
            KTILE(0, gAc, 2 * tt + 1, gBc, 2 * tt + 1);
            KTILE(1, gAc, 2 * tt + 2, gBc, 2 * tt + 2);
        }
        KTILE(0, gAc, 15, gBc, 15);
        // t=15: stage u=0 of the NEXT output tile's panels (seamless pipe).
        KTILE(1, gAn2, 0, gBn2, 0);

        // Epilogue for tile g (next tile's first operands already in flight).
        #pragma unroll
        for (int m = 0; m < 8; ++m) {
            #pragma unroll
            for (int j2 = 0; j2 < 4; ++j2) {
                int i = rowB + wm * 128 + m * 16 + q * 4 + j2;
                float p  = pos[i];
                float up = TOPM * p, lo = BOTM * p;
                float rs = 0.0f;
                #pragma unroll
                for (int n = 0; n < 4; ++n) {
                    float sv = acc[m][n][j2];
                    int col = colB + wn * 64 + n * 16 + fr;
                    if (sv <= up && sv >= lo && col != i)
                        rs += __expf((sv - p) * INV_TAU);
                }
                #pragma unroll
                for (int d = 1; d < 16; d <<= 1)
                    rs += __shfl_xor(rs, d);
                if (fr == 0 && rs != 0.0f)
                    atomicAdd(&S[i], rs);
            }
        }
        #pragma unroll
        for (int m2 = 0; m2 < 8; ++m2)
            #pragma unroll
            for (int n2 = 0; n2 < 4; ++n2)
                acc[m2][n2] = (f32x4){0.0f, 0.0f, 0.0f, 0.0f};

        gAc = gAn2; gBc = gBn2; rowB = rowBn; colB = colBn;
    }
    VMC(0);    // drain redundant g=3 staging + atomics before endpgm

#undef BASES
#undef PANELS
#undef STAGE
#undef LDA_
#undef LDB_
#undef MM_
#undef BAR
#undef SCH
#undef LGKM
#undef VMC
#undef PRI1
#undef PRI0
#undef KTILE
}

// ---------------------------------------------------------------------------
// Kernel 3: per_row = log1p(S_i) for rows with any negative; mean over valid.
// ---------------------------------------------------------------------------
__global__ __launch_bounds__(256) void finalize_kernel(
    const float* __restrict__ S, float* __restrict__ out)
{
    int t = threadIdx.x;
    float tot = 0.0f;
    int c = 0;
    for (int i = t; i < BATCH; i += 256) {
        float s = S[i];
        if (s > 0.0f) { tot += log1pf(s); c += 1; }
    }
    #pragma unroll
    for (int d = 32; d > 0; d >>= 1) {
        tot += __shfl_down(tot, d);
        c   += __shfl_down(c, d);
    }
    __shared__ float st[4];
    __shared__ int   sc[4];
    int lane = t & 63, w = t >> 6;
    if (lane == 0) { st[w] = tot; sc[w] = c; }
    __syncthreads();
    if (t == 0) {
        float T = st[0] + st[1] + st[2] + st[3];
        int   C = sc[0] + sc[1] + sc[2] + sc[3];
        out[0] = T / (float)(C > 0 ? C : 1);
    }
}

extern "C" void kernel_launch(void* const* d_in, const int* in_sizes, int n_in,
                              void* d_out, int out_size, void* d_ws, size_t ws_size,
                              hipStream_t stream) {
    const float* A = (const float*)d_in[0];
    const float* B = (const float*)d_in[1];

    char* ws = (char*)d_ws;
    unsigned short* An = (unsigned short*)ws;
    unsigned short* Bn = An + (size_t)BATCH * DIM;
    float* pos = (float*)(Bn + (size_t)BATCH * DIM);
    float* S   = pos + BATCH;
    float* out = (float*)d_out;

    prep_kernel<<<BATCH, 256, 0, stream>>>(A, B, An, Bn, pos, S);
    sim_loss_kernel<<<256, 512, 0, stream>>>(An, Bn, pos, S);
    finalize_kernel<<<1, 256, 0, stream>>>(S, out);
}

// Round 7
// 201.724 us; speedup vs baseline: 1.2900x; 1.0447x over previous
//
#include <hip/hip_runtime.h>
#include <hip/hip_bf16.h>

#define BATCH 8192
#define DIM   1024
#define INV_TAU (1.0f / 0.07f)
#define TOPM 0.95f
#define BOTM 0.05f

#define BM 256
#define BN 256
#define BK 64
#define NT (DIM / BK)   // 16 K-tiles per output tile

typedef __attribute__((ext_vector_type(4))) float f32x4;
typedef __attribute__((ext_vector_type(8))) short bf16x8;

typedef __attribute__((address_space(3))) void       lds_void_t;
typedef const __attribute__((address_space(1))) void gbl_void_t;

__device__ inline void async_copy16(const void* g, void* l) {
    __builtin_amdgcn_global_load_lds((gbl_void_t*)g, (lds_void_t*)l, 16, 0, 0);
}

__device__ inline unsigned short f2bf(float f) {
    __hip_bfloat16 h = __float2bfloat16(f);
    return *reinterpret_cast<unsigned short*>(&h);
}

// ---------------------------------------------------------------------------
// Kernel 1: per-row L2 norms, exact fp32 pos, bf16 writes, zero-init S.
// ---------------------------------------------------------------------------
__global__ __launch_bounds__(256) void prep_kernel(
    const float* __restrict__ A, const float* __restrict__ B,
    unsigned short* __restrict__ An, unsigned short* __restrict__ Bn,
    float* __restrict__ pos, float* __restrict__ S)
{
    int row = blockIdx.x;
    int t = threadIdx.x;
    const float4* a4 = (const float4*)(A + (size_t)row * DIM);
    const float4* b4 = (const float4*)(B + (size_t)row * DIM);
    float4 av = a4[t];
    float4 bv = b4[t];
    float sa = av.x*av.x + av.y*av.y + av.z*av.z + av.w*av.w;
    float sb = bv.x*bv.x + bv.y*bv.y + bv.z*bv.z + bv.w*bv.w;
    float dp = av.x*bv.x + av.y*bv.y + av.z*bv.z + av.w*bv.w;
    #pragma unroll
    for (int d = 32; d > 0; d >>= 1) {
        sa += __shfl_down(sa, d);
        sb += __shfl_down(sb, d);
        dp += __shfl_down(dp, d);
    }
    __shared__ float red[3][4];
    int lane = t & 63, w = t >> 6;
    if (lane == 0) { red[0][w] = sa; red[1][w] = sb; red[2][w] = dp; }
    __syncthreads();
    sa = red[0][0] + red[0][1] + red[0][2] + red[0][3];
    sb = red[1][0] + red[1][1] + red[1][2] + red[1][3];
    dp = red[2][0] + red[2][1] + red[2][2] + red[2][3];
    float ra = rsqrtf(sa);
    float rb = rsqrtf(sb);
    if (t == 0) {
        pos[row] = dp * ra * rb;
        S[row] = 0.0f;
    }
    ushort4 oa, ob;
    oa.x = f2bf(av.x * ra); oa.y = f2bf(av.y * ra);
    oa.z = f2bf(av.z * ra); oa.w = f2bf(av.w * ra);
    ob.x = f2bf(bv.x * rb); ob.y = f2bf(bv.y * rb);
    ob.z = f2bf(bv.z * rb); ob.w = f2bf(bv.w * rb);
    ((ushort4*)(An + (size_t)row * DIM))[t] = oa;
    ((ushort4*)(Bn + (size_t)row * DIM))[t] = ob;
}

// ---------------------------------------------------------------------------
// Kernel 2: PERSISTENT 256x256 MFMA GEMM + fused masked exp-sum.
// SOFT-SEAM schedule: 2 barriers per K-tile, ONE sched_barrier per phase
// (right after the barrier), C++ ds_reads so the compiler interleaves
// MFMA/read-issue with its own per-operand lgkm waits. Explicit lgkmcnt(0)
// only at phase END (stage-over-read WAR before the next barrier). Counted
// vmcnt(4) once per K-tile (no other VMEM in the K-loop, so counts hold).
//
// Per K-tile t (p=t&1; read A[p],B[p]):
//  phX: BAR;SCH; ds a0(8),b0(4),b1(4); stage A(t+1)h0+h1 -> A[p^1];
//       MM00, MM01 (compiler-gated); LGKM0
//  phY: BAR;SCH; ds a1(8); stage B(t+2)h0+h1 -> B[p];
//       MM11, MM10; LGKM0; VMC(4)
// vmcnt ledger at VMC(4): [B(t+1)4][A(t+1)4][B(t+2)4]=12 -> drains
//  B(t+1)+A(t+1), leaves B(t+2). Tile t+1 phX reads A(t+1),B(t+1). OK.
// WAR: stage A[p^1]@phX: its last reads (tile t-1) drained by t-1's LGKM0s
//  before barriers. stage B[p]@phY: this tile's b0/b1 reads drained by phX
//  LGKM0 before BAR(phY). Epilogue pos-loads/atomics are older than next
//  staging -> VMC(4) over-drains them (safe).
// ---------------------------------------------------------------------------
__global__ __launch_bounds__(512, 2) void sim_loss_kernel(
    const unsigned short* __restrict__ An, const unsigned short* __restrict__ Bn,
    const float* __restrict__ pos, float* __restrict__ S)
{
    __shared__ char lds[131072];   // A[2]: 0,32768 ; B[2]: 65536, 98304

    int tid  = threadIdx.x;
    int lane = tid & 63;
    int wave = tid >> 6;
    int wm = wave >> 2, wn = wave & 3;   // 2x4 wave grid, 128x64 per wave
    int fr = lane & 15;
    int q  = lane >> 4;

    int bid = blockIdx.x;   // 0..255

#define BASES(g, rB, cB) do {                                                        \
    int xcd_ = bid & 7, jj_ = bid >> 3;                                              \
    int qr_ = (g) >> 1, qc_ = ((g) & 1) ^ (qr_ & 1);                                 \
    (rB) = (qr_ * 16 + (xcd_ >> 1) * 4 + (jj_ >> 3)) * BM;                           \
    (cB) = (qc_ * 16 + (xcd_ & 1) * 8 + (jj_ & 7)) * BN;                             \
} while (0)

    f32x4 acc[8][4] = {};
    bf16x8 a[4][2];      // current mh half: 4 m-frags x 2 k-slices
    bf16x8 b0[2][2];     // nh0 fragments
    bf16x8 b1[2][2];     // nh1 fragments

    // ds_read addressing (read-side swizzle)
    int sw = (fr & 7) << 4;
    int c0 = (q * 16) ^ sw;
    int c1 = (64 + q * 16) ^ sw;
    int aRow = (wm * 128 + fr) * 128;
    int bRow = (wn * 64 + fr) * 128;

    // staging addressing (source-side swizzle, linear LDS dest)
    int strow = tid >> 3;                                  // 0..63
    int scb   = ((tid & 7) * 16) ^ ((strow & 7) << 4);
    int ldst = tid * 16;

#define PANELS(rB, cB, pA, pB) do {                                                  \
    (pA) = (const char*)An + (size_t)((rB) + strow) * 2048 + scb;                    \
    (pB) = (const char*)Bn + (size_t)((cB) + strow) * 2048 + scb;                    \
} while (0)

#define STAGE(gbase, u, h, ldsdst) do {                                              \
    async_copy16((gbase) + (size_t)(h) * 262144 + (size_t)(u) * 128,                 \
                 (ldsdst) + (h) * 16384 + ldst);                                     \
    async_copy16((gbase) + (size_t)(h) * 262144 + 131072 + (size_t)(u) * 128,        \
                 (ldsdst) + (h) * 16384 + 8192 + ldst);                              \
} while (0)

#define LDA_(p, mh) do {                                                             \
    const char* _s = lds + (p) * 32768;                                              \
    _Pragma("unroll") for (int m = 0; m < 4; ++m) {                                  \
        a[m][0] = *(const bf16x8*)(_s + aRow + (mh) * 8192 + m * 2048 + c0);         \
        a[m][1] = *(const bf16x8*)(_s + aRow + (mh) * 8192 + m * 2048 + c1);         \
    }                                                                                \
} while (0)

#define LDB_(arr, p, nh) do {                                                        \
    const char* _s = lds + 65536 + (p) * 32768;                                      \
    _Pragma("unroll") for (int n = 0; n < 2; ++n) {                                  \
        arr[n][0] = *(const bf16x8*)(_s + bRow + (nh) * 4096 + n * 2048 + c0);       \
        arr[n][1] = *(const bf16x8*)(_s + bRow + (nh) * 4096 + n * 2048 + c1);       \
    }                                                                                \
} while (0)

#define MM_(barr, mo, no) do {                                                       \
    _Pragma("unroll") for (int m = 0; m < 4; ++m)                                    \
    _Pragma("unroll") for (int n = 0; n < 2; ++n) {                                  \
        acc[(mo)+m][(no)+n] = __builtin_amdgcn_mfma_f32_16x16x32_bf16(               \
            a[m][0], barr[n][0], acc[(mo)+m][(no)+n], 0, 0, 0);                      \
        acc[(mo)+m][(no)+n] = __builtin_amdgcn_mfma_f32_16x16x32_bf16(               \
            a[m][1], barr[n][1], acc[(mo)+m][(no)+n], 0, 0, 0);                      \
    }                                                                                \
} while (0)

#define BAR() __builtin_amdgcn_s_barrier()
#define SCH() __builtin_amdgcn_sched_barrier(0)
#define LGKM0() asm volatile("s_waitcnt lgkmcnt(0)" ::: "memory")
#define VMC(n)  asm volatile("s_waitcnt vmcnt(" #n ")" ::: "memory")
#define PRI1() __builtin_amdgcn_s_setprio(1)
#define PRI0() __builtin_amdgcn_s_setprio(0)

#define KTILE(p, pA_, uA, pB_, uB) do {                                              \
    char* stA = lds + ((p) ^ 1) * 32768;                                             \
    char* stB = lds + 65536 + (p) * 32768;                                           \
    /* phX: quads (mh0,nh0),(mh0,nh1) */                                             \
    BAR(); SCH();                                                                    \
    LDA_((p), 0); LDB_(b0, (p), 0); LDB_(b1, (p), 1);                                \
    STAGE((pA_), (uA), 0, stA); STAGE((pA_), (uA), 1, stA);                          \
    PRI1(); MM_(b0, 0, 0); MM_(b1, 0, 2); PRI0();                                    \
    LGKM0();                                                                         \
    /* phY: quads (mh1,nh1),(mh1,nh0) */                                             \
    BAR(); SCH();                                                                    \
    LDA_((p), 1);                                                                    \
    STAGE((pB_), (uB), 0, stB); STAGE((pB_), (uB), 1, stB);                          \
    PRI1(); MM_(b1, 4, 2); MM_(b0, 4, 0); PRI0();                                    \
    LGKM0(); VMC(4);                                                                 \
} while (0)

    int rowB, colB;
    BASES(0, rowB, colB);
    const char *gAc, *gBc;
    PANELS(rowB, colB, gAc, gBc);

    // Prologue (once): A(0)->A[0], B(0)->B[0], B(1)->B[1]; drain to 4.
    STAGE(gAc, 0, 0, lds);
    STAGE(gAc, 0, 1, lds);
    STAGE(gBc, 0, 0, lds + 65536);
    STAGE(gBc, 0, 1, lds + 65536);
    STAGE(gBc, 1, 0, lds + 98304);
    STAGE(gBc, 1, 1, lds + 98304);
    VMC(4);

    #pragma unroll 1
    for (int g = 0; g < 4; ++g) {
        int gn = (g < 3) ? g + 1 : 3;
        int rowBn, colBn;
        BASES(gn, rowBn, colBn);
        const char *gAn2, *gBn2;
        PANELS(rowBn, colBn, gAn2, gBn2);

        #pragma unroll 1
        for (int tt = 0; tt < 7; ++tt) {
            KTILE(0, gAc, 2 * tt + 1, gBc, 2 * tt + 2);
            KTILE(1, gAc, 2 * tt + 2, gBc, 2 * tt + 3);
        }
        // t=14: A(15); B wraps to next tile's B(0).
        KTILE(0, gAc, 15, gBn2, 0);
        // t=15: A wraps to next A(0); B to next B(1).
        KTILE(1, gAn2, 0, gBn2, 1);

        // Epilogue for tile g (next tile's first operands already in flight).
        #pragma unroll
        for (int m = 0; m < 8; ++m) {
            #pragma unroll
            for (int j2 = 0; j2 < 4; ++j2) {
                int i = rowB + wm * 128 + m * 16 + q * 4 + j2;
                float p  = pos[i];
                float up = TOPM * p, lo = BOTM * p;
                float rs = 0.0f;
                #pragma unroll
                for (int n = 0; n < 4; ++n) {
                    float sv = acc[m][n][j2];
                    int col = colB + wn * 64 + n * 16 + fr;
                    if (sv <= up && sv >= lo && col != i)
                        rs += __expf((sv - p) * INV_TAU);
                }
                #pragma unroll
                for (int d = 1; d < 16; d <<= 1)
                    rs += __shfl_xor(rs, d);
                if (fr == 0 && rs != 0.0f)
                    atomicAdd(&S[i], rs);
            }
        }
        #pragma unroll
        for (int m2 = 0; m2 < 8; ++m2)
            #pragma unroll
            for (int n2 = 0; n2 < 4; ++n2)
                acc[m2][n2] = (f32x4){0.0f, 0.0f, 0.0f, 0.0f};

        gAc = gAn2; gBc = gBn2; rowB = rowBn; colB = colBn;
    }
    LGKM0();
    VMC(0);    // drain redundant g=3 staging + atomics before endpgm

#undef BASES
#undef PANELS
#undef STAGE
#undef LDA_
#undef LDB_
#undef MM_
#undef BAR
#undef SCH
#undef LGKM0
#undef VMC
#undef PRI1
#undef PRI0
#undef KTILE
}

// ---------------------------------------------------------------------------
// Kernel 3: per_row = log1p(S_i) for rows with any negative; mean over valid.
// ---------------------------------------------------------------------------
__global__ __launch_bounds__(256) void finalize_kernel(
    const float* __restrict__ S, float* __restrict__ out)
{
    int t = threadIdx.x;
    float tot = 0.0f;
    int c = 0;
    for (int i = t; i < BATCH; i += 256) {
        float s = S[i];
        if (s > 0.0f) { tot += log1pf(s); c += 1; }
    }
    #pragma unroll
    for (int d = 32; d > 0; d >>= 1) {
        tot += __shfl_down(tot, d);
        c   += __shfl_down(c, d);
    }
    __shared__ float st[4];
    __shared__ int   sc[4];
    int lane = t & 63, w = t >> 6;
    if (lane == 0) { st[w] = tot; sc[w] = c; }
    __syncthreads();
    if (t == 0) {
        float T = st[0] + st[1] + st[2] + st[3];
        int   C = sc[0] + sc[1] + sc[2] + sc[3];
        out[0] = T / (float)(C > 0 ? C : 1);
    }
}

extern "C" void kernel_launch(void* const* d_in, const int* in_sizes, int n_in,
                              void* d_out, int out_size, void* d_ws, size_t ws_size,
                              hipStream_t stream) {
    const float* A = (const float*)d_in[0];
    const float* B = (const float*)d_in[1];

    char* ws = (char*)d_ws;
    unsigned short* An = (unsigned short*)ws;
    unsigned short* Bn = An + (size_t)BATCH * DIM;
    float* pos = (float*)(Bn + (size_t)BATCH * DIM);
    float* S   = pos + BATCH;
    float* out = (float*)d_out;

    prep_kernel<<<BATCH, 256, 0, stream>>>(A, B, An, Bn, pos, S);
    sim_loss_kernel<<<256, 512, 0, stream>>>(An, Bn, pos, S);
    finalize_kernel<<<1, 256, 0, stream>>>(S, out);
}